// Round 2
// baseline (574.196 us; speedup 1.0000x reference)
//
#include <hip/hip_runtime.h>

// ---------------------------------------------------------------------------
// CausalAttention: B=8, S=2048, D=1024, fp32 in, fp32 out.
// Round 7: GEMM core rebuilt on the 256^2 deep-pipeline template (T3+T4):
//   - BM=BN=256, BK=64, 8 waves (2Mx4N), 512 threads, acc[8][4] per wave
//   - LDS 128KB: 2 slots x 2 ksub-units x {A,B}; unit = 256 rows x 32 cols,
//     stored k-major [col8][row][8] -> frag ds_read_b128 is conflict-free
//     by construction (16 lanes hit consecutive 16B chunks), glds dest linear
//   - 2 lockstep phases per K-tile (2 barriers each); every unit staged
//     exactly 3 phases before consumption; counted s_waitcnt vmcnt(12)
//     steady-state, epilogue drain 12/8/4/0  (never vmcnt(0) mid-loop)
//   - T5 setprio(1) around the 32-MFMA cluster
//   ws: Q 32 | K 32 | Vt 32 | Sc 64  (xh@Sc+0 32MB, Wh@Sc+32MB 6MB)
// ---------------------------------------------------------------------------

typedef _Float16 v8h __attribute__((ext_vector_type(8)));
typedef _Float16 v4h __attribute__((ext_vector_type(4)));
typedef float    v4f __attribute__((ext_vector_type(4)));

#define BM 256
#define BN 256
#define BK 64

__device__ __forceinline__ void async16(const _Float16* g, _Float16* l) {
  // global -> LDS direct copy, 16B/lane; LDS dest = wave-uniform base,
  // HW adds lane*16.  [validated r4]
  __builtin_amdgcn_global_load_lds(
      (__attribute__((address_space(1))) void*)(void*)g,
      (__attribute__((address_space(3))) void*)l, 16, 0, 0);
}

// Stage the (tile t, ksub ks) 256x32 unit of A and of B into LDS.
// LDS unit layout: chunk c (16B) = (row = c&255, col8 = c>>8), i.e. k-major
// [col8][row][8]h. 4 glds/thread per call.
__device__ __forceinline__ void stage_pair(const _Float16* GA, int lda,
                                           const _Float16* GB, int ldb,
                                           _Float16* lds, int t, int ks,
                                           int w, int lane) {
  _Float16* UA = lds + ((size_t)((t & 1) * 2 + ks)) * 8192;
  _Float16* UB = lds + 32768 + ((size_t)((t & 1) * 2 + ks)) * 8192;
  const _Float16* ga = GA + t * 64 + ks * 32;
  const _Float16* gb = GB + t * 64 + ks * 32;
#pragma unroll
  for (int g = 0; g < 2; ++g) {
    const int cb = g * 512 + w * 64;          // wave-uniform chunk base
    const int c = cb + lane;
    const int row = c & 255, col8 = c >> 8;
    async16(ga + (size_t)row * lda + col8 * 8, UA + cb * 8);
    async16(gb + (size_t)row * ldb + col8 * 8, UB + cb * 8);
  }
}

// One ksub phase: 12 ds_read_b128 + 32 MFMA. UA/UB point at the unit.
__device__ __forceinline__ void mfma_phase(const _Float16* UA, const _Float16* UB,
                                           int wr, int wc, int lr, int quad,
                                           v4f acc[8][4]) {
  v8h a[8], b[4];
#pragma unroll
  for (int i = 0; i < 8; ++i)
    a[i] = *(const v8h*)&UA[(quad * 256 + wr + i * 16 + lr) * 8];
#pragma unroll
  for (int j = 0; j < 4; ++j)
    b[j] = *(const v8h*)&UB[(quad * 256 + wc + j * 16 + lr) * 8];
  __builtin_amdgcn_s_setprio(1);
#pragma unroll
  for (int i = 0; i < 8; ++i)
#pragma unroll
    for (int j = 0; j < 4; ++j)
      acc[i][j] = __builtin_amdgcn_mfma_f32_16x16x32_f16(a[i], b[j],
                                                         acc[i][j], 0, 0, 0);
  __builtin_amdgcn_s_setprio(0);
}

// Deep-pipelined K loop. Phase P=2kt+ph consumes unit(kt, ph) staged at P-3.
// Stage schedule: P=2kt+0 stages ksub1[kt+1]; P=2kt+1 stages ksub0[kt+2].
// vmcnt counts: 4 glds per staging phase -> steady vmcnt(12); drain 8/4/0.
__device__ __forceinline__ void gemm_loop(const _Float16* Ab, int lda,
                                          const _Float16* Bb, int ldb,
                                          int NK, _Float16* lds,
                                          int w, int lane, int wr, int wc,
                                          int lr, int quad, v4f acc[8][4]) {
  // prologue: units for tiles 0 and 1 (consumed at P=0,1,2)
  stage_pair(Ab, lda, Bb, ldb, lds, 0, 0, w, lane);
  stage_pair(Ab, lda, Bb, ldb, lds, 0, 1, w, lane);
  stage_pair(Ab, lda, Bb, ldb, lds, 1, 0, w, lane);

#define PH(KS, SLOT, DOSTAGE, ST, SKS, VM)                                   \
  do {                                                                       \
    if (DOSTAGE) stage_pair(Ab, lda, Bb, ldb, lds, ST, SKS, w, lane);        \
    asm volatile("s_waitcnt vmcnt(" #VM ")" ::: "memory");                   \
    asm volatile("" ::: "memory");                                           \
    __builtin_amdgcn_s_barrier();                                            \
    asm volatile("" ::: "memory");                                           \
    mfma_phase(lds + ((size_t)((SLOT) * 2 + (KS))) * 8192,                   \
               lds + 32768 + ((size_t)((SLOT) * 2 + (KS))) * 8192,           \
               wr, wc, lr, quad, acc);                                       \
    asm volatile("" ::: "memory");                                           \
    __builtin_amdgcn_s_barrier();                                            \
    asm volatile("" ::: "memory");                                           \
  } while (0)

  for (int kt = 0; kt < NK - 2; ++kt) {
    const int sl = kt & 1;
    PH(0, sl, true, kt + 1, 1, 12);
    PH(1, sl, true, kt + 2, 0, 12);
  }
  {
    const int kt = NK - 2, sl = kt & 1;
    PH(0, sl, true, kt + 1, 1, 12);
    PH(1, sl, false, 0, 0, 8);
  }
  {
    const int kt = NK - 1, sl = kt & 1;
    PH(0, sl, false, 0, 0, 4);
    PH(1, sl, false, 0, 0, 0);
  }
#undef PH
}

// Bijective XCD-aware swizzle of the per-z 2D grid (requires nwg%8==0:
// proj 768, scores 64, pv 32 — all divisible).
__device__ __forceinline__ void grid_swz(int& bx, int& by) {
  const int gx = gridDim.x;
  const int n = gx * gridDim.y;
  const int f = blockIdx.x + blockIdx.y * gx;
  const int s = (f & 7) * (n >> 3) + (f >> 3);
  bx = s % gx;
  by = s / gx;
}

// ---------------------------------------------------------------------------
// fp32 -> fp16, 8 elems/thread.
// ---------------------------------------------------------------------------
__global__ __launch_bounds__(256)
void cvt_f16(const float* __restrict__ src, _Float16* __restrict__ dst) {
  const int i = (blockIdx.x * 256 + threadIdx.x) * 8;
  float4 a = *(const float4*)(src + i);
  float4 b = *(const float4*)(src + i + 4);
  v8h o = {(_Float16)a.x, (_Float16)a.y, (_Float16)a.z, (_Float16)a.w,
           (_Float16)b.x, (_Float16)b.y, (_Float16)b.z, (_Float16)b.w};
  *(v8h*)(dst + i) = o;
}

// ---------------------------------------------------------------------------
// Projection: C[m][n] = X[m][:] . W[n][:], n in [0,3072) packed Q|K|V.
// Q,K stored [16384][1024]; V transposed Vt[b][d][s].
// ---------------------------------------------------------------------------
__global__ __launch_bounds__(512, 2)
void proj_gemm(const _Float16* __restrict__ X, const _Float16* __restrict__ W,
               _Float16* __restrict__ Qb, _Float16* __restrict__ Kb,
               _Float16* __restrict__ Vt) {
  __shared__ _Float16 lds[65536];
  const int tid = threadIdx.x;
  int bx, by;
  grid_swz(bx, by);
  const int n0 = bx * BN, m0 = by * BM;
  const int which = n0 >> 10;                    // 0=Q 1=K 2=V, block-uniform
  const int nw = n0 & 1023;

  const int lane = tid & 63, w = tid >> 6;
  const int wr = (w >> 2) * 128, wc = (w & 3) * 64;
  const int lr = lane & 15, quad = lane >> 4;

  v4f acc[8][4];
#pragma unroll
  for (int i = 0; i < 8; ++i)
#pragma unroll
    for (int j = 0; j < 4; ++j) acc[i][j] = (v4f){0.f, 0.f, 0.f, 0.f};

  gemm_loop(X + (size_t)m0 * 1024, 1024, W + (size_t)n0 * 1024, 1024,
            1024 / BK, lds, w, lane, wr, wc, lr, quad, acc);

  // C/D layout: col = lane&15, row = quad*4 + reg  [validated r4]
#pragma unroll
  for (int i = 0; i < 8; ++i) {
    const int r0 = m0 + wr + i * 16 + quad * 4;
#pragma unroll
    for (int j = 0; j < 4; ++j) {
      const int cl = wc + j * 16 + lr;
      if (which < 2) {
        _Float16* dst = (which == 0) ? Qb : Kb;
        const int col = nw + cl;
#pragma unroll
        for (int rg = 0; rg < 4; ++rg)
          dst[(size_t)(r0 + rg) * 1024 + col] = (_Float16)acc[i][j][rg];
      } else {
        const int d = nw + cl;
        const int b = r0 >> 11, s = r0 & 2047;   // 4 rows stay in-batch
        v4h o = {(_Float16)acc[i][j][0], (_Float16)acc[i][j][1],
                 (_Float16)acc[i][j][2], (_Float16)acc[i][j][3]};
        *(v4h*)(Vt + (size_t)b * 1024 * 2048 + (size_t)d * 2048 + s) = o;
      }
    }
  }
}

// ---------------------------------------------------------------------------
// Scores: Sc[b][q][k] = Q[b][q][:].K[b][k][:] (f16 raw), -inf where k > q.
// ---------------------------------------------------------------------------
__global__ __launch_bounds__(512, 2)
void scores_gemm(const _Float16* __restrict__ Q, const _Float16* __restrict__ K,
                 _Float16* __restrict__ Sc) {
  __shared__ _Float16 lds[65536];
  const int tid = threadIdx.x;
  int bx, by;
  grid_swz(bx, by);
  const int bz = blockIdx.z;
  const int n0 = bx * BN, m0 = by * BM;
  _Float16* Cb = Sc + (size_t)bz * 2048 * 2048;

  if (bx > by) {                                 // fully masked tile
    const _Float16 ninf = (_Float16)(-__builtin_inff());
    v8h mv = {ninf, ninf, ninf, ninf, ninf, ninf, ninf, ninf};
#pragma unroll
    for (int it = 0; it < 16; ++it) {
      int ch = it * 512 + tid;                   // v8h chunk in 256x256 tile
      int r = ch >> 5, cc = (ch & 31) * 8;
      *(v8h*)(Cb + (size_t)(m0 + r) * 2048 + n0 + cc) = mv;
    }
    return;
  }

  const _Float16* Qz = Q + (size_t)bz * 2048 * 1024;
  const _Float16* Kz = K + (size_t)bz * 2048 * 1024;

  const int lane = tid & 63, w = tid >> 6;
  const int wr = (w >> 2) * 128, wc = (w & 3) * 64;
  const int lr = lane & 15, quad = lane >> 4;

  v4f acc[8][4];
#pragma unroll
  for (int i = 0; i < 8; ++i)
#pragma unroll
    for (int j = 0; j < 4; ++j) acc[i][j] = (v4f){0.f, 0.f, 0.f, 0.f};

  gemm_loop(Qz + (size_t)m0 * 1024, 1024, Kz + (size_t)n0 * 1024, 1024,
            1024 / BK, lds, w, lane, wr, wc, lr, quad, acc);

  const _Float16 ninf = (_Float16)(-__builtin_inff());
#pragma unroll
  for (int i = 0; i < 8; ++i) {
    const int r0 = m0 + wr + i * 16 + quad * 4;
#pragma unroll
    for (int j = 0; j < 4; ++j) {
      const int cc = n0 + wc + j * 16 + lr;
#pragma unroll
      for (int rg = 0; rg < 4; ++rg) {
        const int rr = r0 + rg;
        Cb[(size_t)rr * 2048 + cc] = (cc > rr) ? ninf : (_Float16)acc[i][j][rg];
      }
    }
  }
}

// ---------------------------------------------------------------------------
// Row softmax in place (f16), scale 1/32 inside exp.
// ---------------------------------------------------------------------------
__global__ __launch_bounds__(256)
void softmax_rows(_Float16* __restrict__ Sc) {
  _Float16* base = Sc + (size_t)blockIdx.x * 2048;
  const int tid = threadIdx.x;
  const int lane = tid & 63, w = tid >> 6;

  v8h pv = *(const v8h*)(base + tid * 8);
  float f[8];
#pragma unroll
  for (int j = 0; j < 8; ++j) f[j] = (float)pv[j];

  float mx = f[0];
#pragma unroll
  for (int j = 1; j < 8; ++j) mx = fmaxf(mx, f[j]);
#pragma unroll
  for (int off = 32; off; off >>= 1) mx = fmaxf(mx, __shfl_xor(mx, off));
  __shared__ float redm[4], reds[4];
  if (lane == 0) redm[w] = mx;
  __syncthreads();
  mx = fmaxf(fmaxf(redm[0], redm[1]), fmaxf(redm[2], redm[3]));

  const float scale = 0.03125f;                  // 1/sqrt(1024)
  float e[8], s = 0.f;
#pragma unroll
  for (int j = 0; j < 8; ++j) {
    e[j] = __expf((f[j] - mx) * scale);
    s += e[j];
  }
#pragma unroll
  for (int off = 32; off; off >>= 1) s += __shfl_xor(s, off);
  if (lane == 0) reds[w] = s;
  __syncthreads();
  s = reds[0] + reds[1] + reds[2] + reds[3];
  const float inv = 1.0f / s;
#pragma unroll
  for (int j = 0; j < 8; ++j) pv[j] = (_Float16)(e[j] * inv);
  *(v8h*)(base + tid * 8) = pv;
}

// ---------------------------------------------------------------------------
// Out (fp32): out[b][q][d] = sum_k P[b][q][k] * Vt[b][d][k]; K-loop causally
// truncated to (by+1)*256  -> NK = (by+1)*4 >= 4 (prologue needs >= 2 tiles).
// ---------------------------------------------------------------------------
__global__ __launch_bounds__(512, 2)
void pv_gemm(const _Float16* __restrict__ P, const _Float16* __restrict__ Vt,
             float* __restrict__ Out) {
  __shared__ _Float16 lds[65536];
  const int tid = threadIdx.x;
  int bx, by;
  grid_swz(bx, by);
  const int bz = blockIdx.z;
  const int n0 = bx * BN, m0 = by * BM;
  const _Float16* Pb = P + (size_t)bz * 2048 * 2048;
  const _Float16* Vb = Vt + (size_t)bz * 1024 * 2048;
  float* Cb = Out + (size_t)bz * 2048 * 1024;

  const int lane = tid & 63, w = tid >> 6;
  const int wr = (w >> 2) * 128, wc = (w & 3) * 64;
  const int lr = lane & 15, quad = lane >> 4;

  v4f acc[8][4];
#pragma unroll
  for (int i = 0; i < 8; ++i)
#pragma unroll
    for (int j = 0; j < 4; ++j) acc[i][j] = (v4f){0.f, 0.f, 0.f, 0.f};

  gemm_loop(Pb + (size_t)m0 * 2048, 2048, Vb + (size_t)n0 * 2048, 2048,
            (by + 1) * 4, lds, w, lane, wr, wc, lr, quad, acc);

#pragma unroll
  for (int i = 0; i < 8; ++i) {
    const int r0 = m0 + wr + i * 16 + quad * 4;
#pragma unroll
    for (int j = 0; j < 4; ++j) {
      const int cc = n0 + wc + j * 16 + lr;
#pragma unroll
      for (int rg = 0; rg < 4; ++rg)
        Cb[(size_t)(r0 + rg) * 1024 + cc] = acc[i][j][rg];   // fp32 store
    }
  }
}

// ---------------------------------------------------------------------------
extern "C" void kernel_launch(void* const* d_in, const int* in_sizes, int n_in,
                              void* d_out, int out_size, void* d_ws, size_t ws_size,
                              hipStream_t stream) {
  const int B = 8, S = 2048, D = 1024;
  const int M = B * S;                           // 16384
  const float* x  = (const float*)d_in[0];
  const float* Wq = (const float*)d_in[1];
  const float* Wk = (const float*)d_in[2];
  const float* Wv = (const float*)d_in[3];
  float* out = (float*)d_out;

  // ws: Q 32MB | K 32MB | Vt 32MB | Sc 64MB (160 MB total, validated r4).
  // xh (32MB) and Wh (6MB) alias the head of Sc — dead before scores writes.
  char* ws = (char*)d_ws;
  _Float16* Qb = (_Float16*)ws;                          // [M][1024]
  _Float16* Kb = (_Float16*)(ws + (size_t)33554432);     // [M][1024]
  _Float16* Vt = (_Float16*)(ws + (size_t)67108864);     // [B][1024][2048]
  _Float16* Sc = (_Float16*)(ws + (size_t)100663296);    // [B][2048][2048]
  _Float16* xh = Sc;                                     // [M][1024]   (alias)
  _Float16* Wh = Sc + (size_t)M * D;                     // [3072][1024](alias)

  // 1) fp32 -> fp16 converts (memory-bound)
  cvt_f16<<<(M * D) / 2048, 256, 0, stream>>>(x, xh);
  cvt_f16<<<(D * D) / 2048, 256, 0, stream>>>(Wq, Wh);
  cvt_f16<<<(D * D) / 2048, 256, 0, stream>>>(Wk, Wh + (size_t)D * D);
  cvt_f16<<<(D * D) / 2048, 256, 0, stream>>>(Wv, Wh + (size_t)2 * D * D);

  // 2) QKV projection (256^2 deep-pipelined GEMM)
  proj_gemm<<<dim3(12, M / BM, 1), 512, 0, stream>>>(xh, Wh, Qb, Kb, Vt);

  // 3) raw scores with causal -inf mask
  scores_gemm<<<dim3(S / BN, S / BM, B), 512, 0, stream>>>(Qb, Kb, Sc);

  // 4) softmax rows in place
  softmax_rows<<<B * S, 256, 0, stream>>>(Sc);

  // 5) out = P @ Vt, fp32 store
  pv_gemm<<<dim3(D / BN, S / BM, B), 512, 0, stream>>>(Sc, Vt, out);
}

// Round 3
// 388.663 us; speedup vs baseline: 1.4774x; 1.4774x over previous
//
#include <hip/hip_runtime.h>

// ---------------------------------------------------------------------------
// CausalAttention: B=8, S=2048, D=1024, fp32 in, fp32 out.
// Round 8: 256^2 deep pipeline (kept from r7) + COALESCED staging (fix of
// r7's regression: k-major LDS forced 2KB-strided 64-lane gathers per glds).
//   - BM=BN=256, BK=32 (one k-tile per phase), 8 waves (2Mx4N), 512 thr
//   - LDS 128KB = 4 slots x {A 16KB, B 16KB}; unit row-major [256][32]h,
//     chunk u -> (row=u>>2, col=u&3): one glds = 16 dense rows  (coalesced)
//   - both-sides XOR swizzle (r6-validated, rule 21): store chunk (row,c) at
//     (row, c ^ ((row>>1)&3)) via pre-swizzled GLOBAL source, same XOR on
//     frag read -> every 16-lane frag read = 2 lanes/bank-group (free)
//   - phase t: [12 ds_read tile t | vmcnt(4) | s_barrier | stage t+3 (4 glds)
//     | setprio(1) 32 MFMA setprio(0)].  Single barrier/phase; lockstep
//     proof: reads of t confirmed at phase t-1's vmcnt+barrier; stage t+3
//     lands in slot (t-1)&3 only after the barrier that follows MFMA_{t-1}
//     which drained all reads of t-1.  vmcnt never 0 mid-loop.
//   ws: Q 32 | K 32 | Vt 32 | Sc 64  (xh@Sc+0 32MB, Wh@Sc+32MB 6MB)
// ---------------------------------------------------------------------------

typedef _Float16 v8h __attribute__((ext_vector_type(8)));
typedef _Float16 v4h __attribute__((ext_vector_type(4)));
typedef float    v4f __attribute__((ext_vector_type(4)));

#define BM 256
#define BN 256

__device__ __forceinline__ void async16(const _Float16* g, _Float16* l) {
  // global -> LDS direct copy, 16B/lane; LDS dest = wave-uniform base,
  // HW adds lane*16.  [validated r4]
  __builtin_amdgcn_global_load_lds(
      (__attribute__((address_space(1))) void*)(void*)g,
      (__attribute__((address_space(3))) void*)l, 16, 0, 0);
}

// ---------------------------------------------------------------------------
// Shared deep-pipelined GEMM loop.  NKT = number of 32-wide k-tiles (>=4).
// Ab/Bb: row-major operand bases (rows = tile rows, lda/ldb = row stride).
// acc[8][4] per wave; wave grid 2Mx4N (wr in {0,128}, wc in {0,64,128,192}).
// ---------------------------------------------------------------------------
__device__ __forceinline__ void gemm_loop(const _Float16* Ab, int lda,
                                          const _Float16* Bb, int ldb,
                                          int NKT, _Float16* lds,
                                          int w, int lane, int wr, int wc,
                                          int lr, int quad, v4f acc[8][4]) {
  // --- per-thread fragment LDS offsets (elements), constant across phases.
  // frag read applies the same XOR the staging pre-applied on the source.
  int offA[8], offB[4];
#pragma unroll
  for (int i = 0; i < 8; ++i) {
    const int row = wr + i * 16 + lr;
    offA[i] = row * 32 + ((quad ^ ((row >> 1) & 3)) * 8);
  }
#pragma unroll
  for (int j = 0; j < 4; ++j) {
    const int row = wc + j * 16 + lr;
    offB[j] = 8192 + row * 32 + ((quad ^ ((row >> 1) & 3)) * 8);
  }

  // --- per-thread staging sources (pre-swizzled global addresses) and
  // wave-uniform LDS dests.  chunk u = w*128 + g*64 + lane; row=u>>2, c=u&3;
  // source col chunk = c ^ ((row>>1)&3)  (involution).
  const int u0 = w * 128 + lane;        // g=0
  const int u1 = u0 + 64;               // g=1
  const int r0 = u0 >> 2, c0 = (u0 & 3) ^ ((r0 >> 1) & 3);
  const int r1 = u1 >> 2, c1 = (u1 & 3) ^ ((r1 >> 1) & 3);
  const _Float16* pA0 = Ab + (size_t)r0 * lda + c0 * 8;
  const _Float16* pA1 = Ab + (size_t)r1 * lda + c1 * 8;
  const _Float16* pB0 = Bb + (size_t)r0 * ldb + c0 * 8;
  const _Float16* pB1 = Bb + (size_t)r1 * ldb + c1 * 8;
  const int dA0 = (w * 128) * 8;        // wave-uniform chunk base * 8 elems
  const int dA1 = (w * 128 + 64) * 8;

#define STAGE(T)                                                             \
  do {                                                                       \
    _Float16* Ld = lds + ((T) & 3) * 16384;                                  \
    async16(pA0 + (T) * 32, Ld + dA0);                                       \
    async16(pB0 + (T) * 32, Ld + 8192 + dA0);                                \
    async16(pA1 + (T) * 32, Ld + dA1);                                       \
    async16(pB1 + (T) * 32, Ld + 8192 + dA1);                                \
  } while (0)

  // --- prologue: stage tiles 0,1,2 (12 glds); confirm tile 0 (retire 4).
  STAGE(0);
  STAGE(1);
  STAGE(2);
  asm volatile("s_waitcnt vmcnt(8)" ::: "memory");
  __builtin_amdgcn_s_barrier();

  for (int t = 0; t < NKT; ++t) {
    const _Float16* U = lds + (t & 3) * 16384;
    v8h a[8], b[4];
#pragma unroll
    for (int i = 0; i < 8; ++i) a[i] = *(const v8h*)(U + offA[i]);
#pragma unroll
    for (int j = 0; j < 4; ++j) b[j] = *(const v8h*)(U + offB[j]);
    // counted vmcnt: confirm tile t+1 resident for next phase's reads.
    // outstanding here: {t+1, t+2} (8) steady; {t+1} (4) at t==NKT-2.
    if (t < NKT - 2) {
      asm volatile("s_waitcnt vmcnt(4)" ::: "memory");
    } else {
      asm volatile("s_waitcnt vmcnt(0)" ::: "memory");
    }
    __builtin_amdgcn_s_barrier();
    if (t + 3 < NKT) STAGE(t + 3);     // slot (t-1)&3: all reads done (see hdr)
    __builtin_amdgcn_s_setprio(1);
#pragma unroll
    for (int i = 0; i < 8; ++i)
#pragma unroll
      for (int j = 0; j < 4; ++j)
        acc[i][j] = __builtin_amdgcn_mfma_f32_16x16x32_f16(a[i], b[j],
                                                           acc[i][j], 0, 0, 0);
    __builtin_amdgcn_s_setprio(0);
    __builtin_amdgcn_sched_barrier(0);
  }
#undef STAGE
}

// Bijective XCD-aware swizzle of the per-z 2D grid (requires nwg%8==0:
// proj 768, scores 64, pv 32 — all divisible).
__device__ __forceinline__ void grid_swz(int& bx, int& by) {
  const int gx = gridDim.x;
  const int n = gx * gridDim.y;
  const int f = blockIdx.x + blockIdx.y * gx;
  const int s = (f & 7) * (n >> 3) + (f >> 3);
  bx = s % gx;
  by = s / gx;
}

// ---------------------------------------------------------------------------
// fp32 -> fp16, 8 elems/thread.
// ---------------------------------------------------------------------------
__global__ __launch_bounds__(256)
void cvt_f16(const float* __restrict__ src, _Float16* __restrict__ dst) {
  const int i = (blockIdx.x * 256 + threadIdx.x) * 8;
  float4 a = *(const float4*)(src + i);
  float4 b = *(const float4*)(src + i + 4);
  v8h o = {(_Float16)a.x, (_Float16)a.y, (_Float16)a.z, (_Float16)a.w,
           (_Float16)b.x, (_Float16)b.y, (_Float16)b.z, (_Float16)b.w};
  *(v8h*)(dst + i) = o;
}

// ---------------------------------------------------------------------------
// Projection: C[m][n] = X[m][:] . W[n][:], n in [0,3072) packed Q|K|V.
// Q,K stored [16384][1024]; V transposed Vt[b][d][s].
// ---------------------------------------------------------------------------
__global__ __launch_bounds__(512, 2)
void proj_gemm(const _Float16* __restrict__ X, const _Float16* __restrict__ W,
               _Float16* __restrict__ Qb, _Float16* __restrict__ Kb,
               _Float16* __restrict__ Vt) {
  __shared__ _Float16 lds[65536];
  const int tid = threadIdx.x;
  int bx, by;
  grid_swz(bx, by);
  const int n0 = bx * BN, m0 = by * BM;
  const int which = n0 >> 10;                    // 0=Q 1=K 2=V, block-uniform
  const int nw = n0 & 1023;

  const int lane = tid & 63, w = tid >> 6;
  const int wr = (w >> 2) * 128, wc = (w & 3) * 64;
  const int lr = lane & 15, quad = lane >> 4;

  v4f acc[8][4];
#pragma unroll
  for (int i = 0; i < 8; ++i)
#pragma unroll
    for (int j = 0; j < 4; ++j) acc[i][j] = (v4f){0.f, 0.f, 0.f, 0.f};

  gemm_loop(X + (size_t)m0 * 1024, 1024, W + (size_t)n0 * 1024, 1024,
            32, lds, w, lane, wr, wc, lr, quad, acc);

  // C/D layout: col = lane&15, row = quad*4 + reg  [validated r4]
#pragma unroll
  for (int i = 0; i < 8; ++i) {
    const int r0 = m0 + wr + i * 16 + quad * 4;
#pragma unroll
    for (int j = 0; j < 4; ++j) {
      const int cl = wc + j * 16 + lr;
      if (which < 2) {
        _Float16* dst = (which == 0) ? Qb : Kb;
        const int col = nw + cl;
#pragma unroll
        for (int rg = 0; rg < 4; ++rg)
          dst[(size_t)(r0 + rg) * 1024 + col] = (_Float16)acc[i][j][rg];
      } else {
        const int d = nw + cl;
        const int b = r0 >> 11, s = r0 & 2047;   // 4 rows stay in-batch
        v4h o = {(_Float16)acc[i][j][0], (_Float16)acc[i][j][1],
                 (_Float16)acc[i][j][2], (_Float16)acc[i][j][3]};
        *(v4h*)(Vt + (size_t)b * 1024 * 2048 + (size_t)d * 2048 + s) = o;
      }
    }
  }
}

// ---------------------------------------------------------------------------
// Scores: Sc[b][q][k] = Q[b][q][:].K[b][k][:] (f16 raw), -inf where k > q.
// ---------------------------------------------------------------------------
__global__ __launch_bounds__(512, 2)
void scores_gemm(const _Float16* __restrict__ Q, const _Float16* __restrict__ K,
                 _Float16* __restrict__ Sc) {
  __shared__ _Float16 lds[65536];
  const int tid = threadIdx.x;
  int bx, by;
  grid_swz(bx, by);
  const int bz = blockIdx.z;
  const int n0 = bx * BN, m0 = by * BM;
  _Float16* Cb = Sc + (size_t)bz * 2048 * 2048;

  if (bx > by) {                                 // fully masked tile
    const _Float16 ninf = (_Float16)(-__builtin_inff());
    v8h mv = {ninf, ninf, ninf, ninf, ninf, ninf, ninf, ninf};
#pragma unroll
    for (int it = 0; it < 16; ++it) {
      int ch = it * 512 + tid;                   // v8h chunk in 256x256 tile
      int r = ch >> 5, cc = (ch & 31) * 8;
      *(v8h*)(Cb + (size_t)(m0 + r) * 2048 + n0 + cc) = mv;
    }
    return;
  }

  const _Float16* Qz = Q + (size_t)bz * 2048 * 1024;
  const _Float16* Kz = K + (size_t)bz * 2048 * 1024;

  const int lane = tid & 63, w = tid >> 6;
  const int wr = (w >> 2) * 128, wc = (w & 3) * 64;
  const int lr = lane & 15, quad = lane >> 4;

  v4f acc[8][4];
#pragma unroll
  for (int i = 0; i < 8; ++i)
#pragma unroll
    for (int j = 0; j < 4; ++j) acc[i][j] = (v4f){0.f, 0.f, 0.f, 0.f};

  gemm_loop(Qz + (size_t)m0 * 1024, 1024, Kz + (size_t)n0 * 1024, 1024,
            32, lds, w, lane, wr, wc, lr, quad, acc);

  const _Float16 ninf = (_Float16)(-__builtin_inff());
#pragma unroll
  for (int i = 0; i < 8; ++i) {
    const int r0 = m0 + wr + i * 16 + quad * 4;
#pragma unroll
    for (int j = 0; j < 4; ++j) {
      const int cc = n0 + wc + j * 16 + lr;
#pragma unroll
      for (int rg = 0; rg < 4; ++rg) {
        const int rr = r0 + rg;
        Cb[(size_t)rr * 2048 + cc] = (cc > rr) ? ninf : (_Float16)acc[i][j][rg];
      }
    }
  }
}

// ---------------------------------------------------------------------------
// Row softmax in place (f16), scale 1/32 inside exp.
// ---------------------------------------------------------------------------
__global__ __launch_bounds__(256)
void softmax_rows(_Float16* __restrict__ Sc) {
  _Float16* base = Sc + (size_t)blockIdx.x * 2048;
  const int tid = threadIdx.x;
  const int lane = tid & 63, w = tid >> 6;

  v8h pv = *(const v8h*)(base + tid * 8);
  float f[8];
#pragma unroll
  for (int j = 0; j < 8; ++j) f[j] = (float)pv[j];

  float mx = f[0];
#pragma unroll
  for (int j = 1; j < 8; ++j) mx = fmaxf(mx, f[j]);
#pragma unroll
  for (int off = 32; off; off >>= 1) mx = fmaxf(mx, __shfl_xor(mx, off));
  __shared__ float redm[4], reds[4];
  if (lane == 0) redm[w] = mx;
  __syncthreads();
  mx = fmaxf(fmaxf(redm[0], redm[1]), fmaxf(redm[2], redm[3]));

  const float scale = 0.03125f;                  // 1/sqrt(1024)
  float e[8], s = 0.f;
#pragma unroll
  for (int j = 0; j < 8; ++j) {
    e[j] = __expf((f[j] - mx) * scale);
    s += e[j];
  }
#pragma unroll
  for (int off = 32; off; off >>= 1) s += __shfl_xor(s, off);
  if (lane == 0) reds[w] = s;
  __syncthreads();
  s = reds[0] + reds[1] + reds[2] + reds[3];
  const float inv = 1.0f / s;
#pragma unroll
  for (int j = 0; j < 8; ++j) pv[j] = (_Float16)(e[j] * inv);
  *(v8h*)(base + tid * 8) = pv;
}

// ---------------------------------------------------------------------------
// Out (fp32): out[b][q][d] = sum_k P[b][q][k] * Vt[b][d][k]; K-loop causally
// truncated to (by+1)*256  -> NKT = (by+1)*8 >= 8.
// ---------------------------------------------------------------------------
__global__ __launch_bounds__(512, 2)
void pv_gemm(const _Float16* __restrict__ P, const _Float16* __restrict__ Vt,
             float* __restrict__ Out) {
  __shared__ _Float16 lds[65536];
  const int tid = threadIdx.x;
  int bx, by;
  grid_swz(bx, by);
  const int bz = blockIdx.z;
  const int n0 = bx * BN, m0 = by * BM;
  const _Float16* Pb = P + (size_t)bz * 2048 * 2048;
  const _Float16* Vb = Vt + (size_t)bz * 1024 * 2048;
  float* Cb = Out + (size_t)bz * 2048 * 1024;

  const int lane = tid & 63, w = tid >> 6;
  const int wr = (w >> 2) * 128, wc = (w & 3) * 64;
  const int lr = lane & 15, quad = lane >> 4;

  v4f acc[8][4];
#pragma unroll
  for (int i = 0; i < 8; ++i)
#pragma unroll
    for (int j = 0; j < 4; ++j) acc[i][j] = (v4f){0.f, 0.f, 0.f, 0.f};

  gemm_loop(Pb + (size_t)m0 * 2048, 2048, Vb + (size_t)n0 * 2048, 2048,
            (by + 1) * 8, lds, w, lane, wr, wc, lr, quad, acc);

#pragma unroll
  for (int i = 0; i < 8; ++i) {
    const int r0 = m0 + wr + i * 16 + quad * 4;
#pragma unroll
    for (int j = 0; j < 4; ++j) {
      const int cc = n0 + wc + j * 16 + lr;
#pragma unroll
      for (int rg = 0; rg < 4; ++rg)
        Cb[(size_t)(r0 + rg) * 1024 + cc] = acc[i][j][rg];   // fp32 store
    }
  }
}

// ---------------------------------------------------------------------------
extern "C" void kernel_launch(void* const* d_in, const int* in_sizes, int n_in,
                              void* d_out, int out_size, void* d_ws, size_t ws_size,
                              hipStream_t stream) {
  const int B = 8, S = 2048, D = 1024;
  const int M = B * S;                           // 16384
  const float* x  = (const float*)d_in[0];
  const float* Wq = (const float*)d_in[1];
  const float* Wk = (const float*)d_in[2];
  const float* Wv = (const float*)d_in[3];
  float* out = (float*)d_out;

  // ws: Q 32MB | K 32MB | Vt 32MB | Sc 64MB (160 MB total, validated r4).
  // xh (32MB) and Wh (6MB) alias the head of Sc — dead before scores writes.
  char* ws = (char*)d_ws;
  _Float16* Qb = (_Float16*)ws;                          // [M][1024]
  _Float16* Kb = (_Float16*)(ws + (size_t)33554432);     // [M][1024]
  _Float16* Vt = (_Float16*)(ws + (size_t)67108864);     // [B][1024][2048]
  _Float16* Sc = (_Float16*)(ws + (size_t)100663296);    // [B][2048][2048]
  _Float16* xh = Sc;                                     // [M][1024]   (alias)
  _Float16* Wh = Sc + (size_t)M * D;                     // [3072][1024](alias)

  // 1) fp32 -> fp16 converts (memory-bound)
  cvt_f16<<<(M * D) / 2048, 256, 0, stream>>>(x, xh);
  cvt_f16<<<(D * D) / 2048, 256, 0, stream>>>(Wq, Wh);
  cvt_f16<<<(D * D) / 2048, 256, 0, stream>>>(Wk, Wh + (size_t)D * D);
  cvt_f16<<<(D * D) / 2048, 256, 0, stream>>>(Wv, Wh + (size_t)2 * D * D);

  // 2) QKV projection (256^2 deep-pipelined GEMM, coalesced staging)
  proj_gemm<<<dim3(12, M / BM, 1), 512, 0, stream>>>(xh, Wh, Qb, Kb, Vt);

  // 3) raw scores with causal -inf mask
  scores_gemm<<<dim3(S / BN, S / BM, B), 512, 0, stream>>>(Qb, Kb, Sc);

  // 4) softmax rows in place
  softmax_rows<<<B * S, 256, 0, stream>>>(Sc);

  // 5) out = P @ Vt, fp32 store
  pv_gemm<<<dim3(D / BN, S / BM, B), 512, 0, stream>>>(Sc, Vt, out);
}